// Round 17
// baseline (142.491 us; speedup 1.0000x reference)
//
#include <hip/hip_runtime.h>

#define BATCH 2
#define SEQL 1024
#define DMODEL 1024
#define DINNER 2048
#define DSTATE 16
#define DTRANK 64
#define NCH 64
#define LC 16   // SEQL / NCH

typedef short bf16x8 __attribute__((ext_vector_type(8)));
typedef float f32x4 __attribute__((ext_vector_type(4)));
typedef int i32x4 __attribute__((ext_vector_type(4)));

__device__ __forceinline__ unsigned short f2bf(float f) {
  unsigned u = __float_as_uint(f);
  return (unsigned short)((u + 0x7fffu + ((u >> 16) & 1u)) >> 16);
}
__device__ __forceinline__ float bf2f(unsigned short u) {
  return __uint_as_float((unsigned)u << 16);
}
__device__ __forceinline__ float sigmoidf_(float x) { return 1.f / (1.f + __expf(-x)); }

__device__ __forceinline__ void gl_lds16(const unsigned short* g, unsigned short* l) {
  __builtin_amdgcn_global_load_lds(
      (const __attribute__((address_space(1))) unsigned int*)g,
      (__attribute__((address_space(3))) unsigned int*)l, 16, 0, 0);
}

// ---------------- 128x64-tile MFMA GEMM ----------------
// mode 1: C2 = bf16(softplus(acc+bias)) | mode 2: C2 = bf16 direct
// mode 4: atomicAdd fp32 into C (split-K accumulate; C pre-zeroed)
// XCD-bijective swizzle; (gx*gy) % 8 == 0.
__global__ __launch_bounds__(256) void k_gemm_n64(
    const unsigned short* __restrict__ A,   // [M][K] bf16 bits
    const unsigned short* __restrict__ Bt,  // [N][K] bf16 bits
    float* __restrict__ C, unsigned short* __restrict__ C2,
    int M, int N, int K, const float* __restrict__ bias, int mode)
{
  __shared__ __attribute__((aligned(16))) unsigned short As[128 * 64];
  __shared__ __attribute__((aligned(16))) unsigned short Bs[64 * 64];
  const int tid = threadIdx.x;
  const int wave = tid >> 6, lane = tid & 63;
  const int gx = gridDim.x;
  const int nwg = gx * gridDim.y;
  const int flat = blockIdx.x + gx * blockIdx.y;
  const int sw = (flat & 7) * (nwg >> 3) + (flat >> 3);
  const int m0 = (sw % gx) * 128, n0 = (sw / gx) * 64;
  const int Kc = K / gridDim.z;
  const int k0beg = blockIdx.z * Kc;
  const int wr = (wave & 1) * 64, wc = (wave >> 1) * 32;
  const int fr = lane & 15;
  const int qw = lane >> 4;

  int srowA[4], scolA[4];
  #pragma unroll
  for (int i = 0; i < 4; ++i) {
    int off = wave * 4096 + i * 1024 + lane * 16;
    int row = off >> 7;
    int c16 = ((off >> 4) & 7) ^ (row & 7);
    srowA[i] = row;
    scolA[i] = c16 * 8;
  }
  int srowB[2], scolB[2];
  #pragma unroll
  for (int i = 0; i < 2; ++i) {
    int off = wave * 2048 + i * 1024 + lane * 16;
    int row = off >> 7;
    int c16 = ((off >> 4) & 7) ^ (row & 7);
    srowB[i] = row;
    scolB[i] = c16 * 8;
  }

  f32x4 acc[4][2] = {};
  for (int k0 = k0beg; k0 < k0beg + Kc; k0 += 64) {
    #pragma unroll
    for (int i = 0; i < 4; ++i)
      gl_lds16(A + (size_t)(m0 + srowA[i]) * K + k0 + scolA[i],
               &As[(wave * 4096 + i * 1024) >> 1]);
    #pragma unroll
    for (int i = 0; i < 2; ++i)
      gl_lds16(Bt + (size_t)(n0 + srowB[i]) * K + k0 + scolB[i],
               &Bs[(wave * 2048 + i * 1024) >> 1]);
    __syncthreads();
    #pragma unroll
    for (int t = 0; t < 2; ++t) {
      bf16x8 af[4], bfv[2];
      #pragma unroll
      for (int i = 0; i < 4; ++i) {
        int row = wr + i * 16 + fr;
        int c16 = (t * 4 + qw) ^ (row & 7);
        af[i] = *(const bf16x8*)&As[row * 64 + c16 * 8];
      }
      #pragma unroll
      for (int j = 0; j < 2; ++j) {
        int row = wc + j * 16 + fr;
        int c16 = (t * 4 + qw) ^ (row & 7);
        bfv[j] = *(const bf16x8*)&Bs[row * 64 + c16 * 8];
      }
      #pragma unroll
      for (int i = 0; i < 4; ++i)
        #pragma unroll
        for (int j = 0; j < 2; ++j)
          acc[i][j] = __builtin_amdgcn_mfma_f32_16x16x32_bf16(af[i], bfv[j], acc[i][j], 0, 0, 0);
    }
    __syncthreads();
  }
  const int rr = qw * 4;
  if (mode == 1) {
    #pragma unroll
    for (int j = 0; j < 2; ++j) {
      float bj = bias[n0 + wc + j * 16 + fr];
      #pragma unroll
      for (int i = 0; i < 4; ++i)
        #pragma unroll
        for (int r = 0; r < 4; ++r) {
          float v = acc[i][j][r] + bj;
          C2[(size_t)(m0 + wr + i * 16 + rr + r) * N + (n0 + wc + j * 16 + fr)] =
              f2bf(__logf(1.f + __expf(v)));
        }
    }
  } else if (mode == 2) {
    #pragma unroll
    for (int i = 0; i < 4; ++i)
      #pragma unroll
      for (int j = 0; j < 2; ++j)
        #pragma unroll
        for (int r = 0; r < 4; ++r)
          C2[(size_t)(m0 + wr + i * 16 + rr + r) * N + (n0 + wc + j * 16 + fr)] =
              f2bf(acc[i][j][r]);
  } else {  // mode 4: atomic accumulate
    #pragma unroll
    for (int i = 0; i < 4; ++i)
      #pragma unroll
      for (int j = 0; j < 2; ++j)
        #pragma unroll
        for (int r = 0; r < 4; ++r)
          atomicAdd(&C[(size_t)(m0 + wr + i * 16 + rr + r) * N + (n0 + wc + j * 16 + fr)],
                    acc[i][j][r]);
  }
}

// ---------------- GEMM3: A reg-staged from fp32 dbl cols 0..63 (+softplus+bias -> bf16) ----------------
// M=2048, N=2048, K=64 (single K-step). Same LDS layout/swizzle as k_gemm_n64.
__global__ __launch_bounds__(256) void k_gemm_dt(
    const float* __restrict__ dblsrc,        // [2048][128] fp32; cols 0..63 = dt_raw
    const unsigned short* __restrict__ Bt,   // wdtt [2048][64]
    unsigned short* __restrict__ C2,         // dtb16 [2048][2048]
    const float* __restrict__ bias)
{
  __shared__ __attribute__((aligned(16))) unsigned short As[128 * 64];
  __shared__ __attribute__((aligned(16))) unsigned short Bs[64 * 64];
  const int tid = threadIdx.x;
  const int wave = tid >> 6, lane = tid & 63;
  const int gx = gridDim.x;
  const int nwg = gx * gridDim.y;
  const int flat = blockIdx.x + gx * blockIdx.y;
  const int sw = (flat & 7) * (nwg >> 3) + (flat >> 3);
  const int m0 = (sw % gx) * 128, n0 = (sw / gx) * 64;
  const int wr = (wave & 1) * 64, wc = (wave >> 1) * 32;
  const int fr = lane & 15;
  const int qw = lane >> 4;

  // A: reg-stage fp32 -> bf16, linear LDS dest + inverse-swizzled source (same layout as gl_lds16 path)
  #pragma unroll
  for (int i = 0; i < 4; ++i) {
    int off = wave * 4096 + i * 1024 + lane * 16;  // byte offset in As
    int row = off >> 7;
    int c16 = ((off >> 4) & 7) ^ (row & 7);
    const float* src = dblsrc + (size_t)(m0 + row) * 128 + c16 * 8;
    f32x4 u0 = *(const f32x4*)src;
    f32x4 u1 = *(const f32x4*)(src + 4);
    unsigned short tmp[8] = {f2bf(u0[0]), f2bf(u0[1]), f2bf(u0[2]), f2bf(u0[3]),
                             f2bf(u1[0]), f2bf(u1[1]), f2bf(u1[2]), f2bf(u1[3])};
    *(i32x4*)&As[off >> 1] = *(i32x4*)tmp;
  }
  // B: direct LDS staging (bf16 source)
  #pragma unroll
  for (int i = 0; i < 2; ++i) {
    int off = wave * 2048 + i * 1024 + lane * 16;
    int row = off >> 7;
    int c16 = ((off >> 4) & 7) ^ (row & 7);
    gl_lds16(Bt + (size_t)(n0 + row) * 64 + c16 * 8,
             &Bs[(wave * 2048 + i * 1024) >> 1]);
  }
  __syncthreads();
  f32x4 acc[4][2] = {};
  #pragma unroll
  for (int t = 0; t < 2; ++t) {
    bf16x8 af[4], bfv[2];
    #pragma unroll
    for (int i = 0; i < 4; ++i) {
      int row = wr + i * 16 + fr;
      int c16 = (t * 4 + qw) ^ (row & 7);
      af[i] = *(const bf16x8*)&As[row * 64 + c16 * 8];
    }
    #pragma unroll
    for (int j = 0; j < 2; ++j) {
      int row = wc + j * 16 + fr;
      int c16 = (t * 4 + qw) ^ (row & 7);
      bfv[j] = *(const bf16x8*)&Bs[row * 64 + c16 * 8];
    }
    #pragma unroll
    for (int i = 0; i < 4; ++i)
      #pragma unroll
      for (int j = 0; j < 2; ++j)
        acc[i][j] = __builtin_amdgcn_mfma_f32_16x16x32_bf16(af[i], bfv[j], acc[i][j], 0, 0, 0);
  }
  const int rr = qw * 4;
  #pragma unroll
  for (int j = 0; j < 2; ++j) {
    float bj = bias[n0 + wc + j * 16 + fr];
    #pragma unroll
    for (int i = 0; i < 4; ++i)
      #pragma unroll
      for (int r = 0; r < 4; ++r) {
        float v = acc[i][j][r] + bj;
        C2[(size_t)(m0 + wr + i * 16 + rr + r) * 2048 + (n0 + wc + j * 16 + fr)] =
            f2bf(__logf(1.f + __expf(v)));
      }
  }
}

// ---------------- shared transpose tile helper ----------------
__device__ __forceinline__ void transpose_tile(
    const float* __restrict__ src, unsigned short* __restrict__ dst,
    int R, int C, int bx, int by, float* t /* [64][65] */)
{
  int bc = bx * 64, br = by * 64;
  int tr = threadIdx.x >> 2;
  int tc = (threadIdx.x & 3) * 16;
  #pragma unroll
  for (int i = 0; i < 4; ++i) {
    float4 v = *(const float4*)(src + (size_t)(br + tr) * C + bc + tc + i * 4);
    t[tr * 65 + tc + i * 4 + 0] = v.x; t[tr * 65 + tc + i * 4 + 1] = v.y;
    t[tr * 65 + tc + i * 4 + 2] = v.z; t[tr * 65 + tc + i * 4 + 3] = v.w;
  }
  __syncthreads();
  unsigned short tmp[16];
  #pragma unroll
  for (int i = 0; i < 16; ++i) tmp[i] = f2bf(t[(tc + i) * 65 + tr]);
  unsigned short* dp = dst + (size_t)(bc + tr) * R + br + tc;
  *(i32x4*)dp = *(i32x4*)&tmp[0];
  *(i32x4*)(dp + 8) = *(i32x4*)&tmp[8];
}

// ---------------- prep1: x->bf16 + W_in^T + zero(out) + zero(dbl) ----------------
__global__ __launch_bounds__(256) void k_prep1(
    const float* __restrict__ x,   unsigned short* __restrict__ xbf,
    const float* __restrict__ Win, unsigned short* __restrict__ wint,
    float* __restrict__ outz, float* __restrict__ dblz)
{
  __shared__ float t[64 * 65];
  int bid = blockIdx.x;
  if (bid < 1024) {
    int i = (bid * 256 + threadIdx.x) * 8;
    float4 a = *(const float4*)(x + i);
    float4 b = *(const float4*)(x + i + 4);
    unsigned short tmp[8] = {f2bf(a.x), f2bf(a.y), f2bf(a.z), f2bf(a.w),
                             f2bf(b.x), f2bf(b.y), f2bf(b.z), f2bf(b.w)};
    *(i32x4*)(xbf + i) = *(i32x4*)tmp;
  } else if (bid < 2048) {
    int tt = bid - 1024;
    transpose_tile(Win, wint, 1024, 4096, tt & 63, tt >> 6, t);
  } else if (bid < 4096) {                 // zero out: 2048*1024 fp32
    int i = ((bid - 2048) * 256 + threadIdx.x) * 4;
    f32x4 z = {};
    *(f32x4*)(outz + i) = z;
  } else {                                  // zero dbl: 2048*128 fp32 (256 blocks)
    int i = ((bid - 4096) * 256 + threadIdx.x) * 4;
    f32x4 z = {};
    *(f32x4*)(dblz + i) = z;
  }
}

// ---------------- conv + SiLU merged with remaining weight prep ----------------
__global__ __launch_bounds__(256) void k_conv_prep(
    const unsigned short* __restrict__ xzb, const float* __restrict__ cw,
    const float* __restrict__ cb, unsigned short* __restrict__ xcb,
    const float* __restrict__ Wout, unsigned short* __restrict__ woutt,
    const float* __restrict__ Wdt,  unsigned short* __restrict__ wdtt,
    const float* __restrict__ Wx,   unsigned short* __restrict__ wxt)
{
  __shared__ float t[64 * 65];
  int bid = blockIdx.x;
  if (bid < 2048) {
    int idx = (bid * 256 + threadIdx.x) * 8;
    int d0 = idx & (DINNER - 1);
    int bl = idx >> 11;
    int l = bl & (SEQL - 1);
    float s[8];
    {
      float4 c0 = *(const float4*)(cb + d0);
      float4 c1 = *(const float4*)(cb + d0 + 4);
      s[0] = c0.x; s[1] = c0.y; s[2] = c0.z; s[3] = c0.w;
      s[4] = c1.x; s[5] = c1.y; s[6] = c1.z; s[7] = c1.w;
    }
    float4 w[8];
    #pragma unroll
    for (int i = 0; i < 8; ++i) w[i] = *(const float4*)(cw + (d0 + i) * 4);
    #pragma unroll
    for (int k = 0; k < 4; ++k) {
      int ll = l - 3 + k;
      if (ll >= 0) {
        bf16x8 v = *(const bf16x8*)&xzb[(size_t)(bl - 3 + k) * 4096 + d0];
        #pragma unroll
        for (int i = 0; i < 8; ++i)
          s[i] += bf2f((unsigned short)v[i]) * ((const float*)&w[i])[k];
      }
    }
    unsigned short o[8];
    #pragma unroll
    for (int i = 0; i < 8; ++i) {
      float r = s[i] * sigmoidf_(s[i]);
      o[i] = f2bf(r);
    }
    *(i32x4*)&xcb[idx] = *(i32x4*)o;
  } else if (bid < 2560) {
    int tt = bid - 2048;
    transpose_tile(Wout, woutt, 2048, 1024, tt & 15, tt >> 4, t);
  } else if (bid < 2592) {
    int tt = bid - 2560;
    transpose_tile(Wdt, wdtt, 64, 2048, tt, 0, t);
  } else {
    int idx = (bid - 2592) * 256 + threadIdx.x;
    int k = idx & (DINNER - 1);
    int n = idx >> 11;
    float v = (n < 96) ? Wx[(size_t)k * 96 + n] : 0.f;
    wxt[idx] = f2bf(v);
  }
}

// ---------------- scan pass A: local scan; hend bf16 + sumdt fp32 ----------------
__global__ __launch_bounds__(256) void k_scan_A(
    const unsigned short* __restrict__ dtb, const unsigned short* __restrict__ xcb,
    const float* __restrict__ dbl, const float* __restrict__ Alog,
    unsigned short* __restrict__ hendb, float* __restrict__ sumdtb)
{
  __shared__ __attribute__((aligned(16))) float bcB[LC][DSTATE];
  int gid = blockIdx.x * 256 + threadIdx.x;  // over B*NCH*DINNER = 262144
  int d = gid & (DINNER - 1);
  int t = gid >> 11;
  int c = t & (NCH - 1);
  int b = t >> 6;
  const int r0 = b * SEQL + c * LC;
  bcB[threadIdx.x >> 4][threadIdx.x & 15] =
      dbl[(size_t)(r0 + (threadIdx.x >> 4)) * 128 + 64 + (threadIdx.x & 15)];
  float As[DSTATE];
  #pragma unroll
  for (int i = 0; i < 4; ++i) {
    f32x4 a = *(const f32x4*)&Alog[d * DSTATE + i * 4];
    #pragma unroll
    for (int j = 0; j < 4; ++j) As[i * 4 + j] = -__expf(a[j]);
  }
  __syncthreads();
  float h[DSTATE];
  #pragma unroll
  for (int s = 0; s < DSTATE; ++s) h[s] = 0.f;
  float sumdt = 0.f;
  #pragma unroll
  for (int li = 0; li < LC; li += 2) {
    float dt0 = bf2f(dtb[(size_t)(r0 + li) * DINNER + d]);
    float xv0 = bf2f(xcb[(size_t)(r0 + li) * DINNER + d]);
    float dt1 = bf2f(dtb[(size_t)(r0 + li + 1) * DINNER + d]);
    float xv1 = bf2f(xcb[(size_t)(r0 + li + 1) * DINNER + d]);
    f32x4 B0[4], B1[4];
    #pragma unroll
    for (int i = 0; i < 4; ++i) B0[i] = *(const f32x4*)&bcB[li][i * 4];
    #pragma unroll
    for (int i = 0; i < 4; ++i) B1[i] = *(const f32x4*)&bcB[li + 1][i * 4];
    float dtx0 = dt0 * xv0, dtx1 = dt1 * xv1;
    sumdt += dt0 + dt1;
    const float* Bv0 = (const float*)B0;
    const float* Bv1 = (const float*)B1;
    #pragma unroll
    for (int s = 0; s < DSTATE; ++s) {
      float dA0 = __expf(dt0 * As[s]);
      h[s] = dA0 * h[s] + dtx0 * Bv0[s];
      float dA1 = __expf(dt1 * As[s]);
      h[s] = dA1 * h[s] + dtx1 * Bv1[s];
    }
  }
  size_t base = ((size_t)(b * NCH + c) * DSTATE) * DINNER + d;
  #pragma unroll
  for (int s = 0; s < DSTATE; ++s) hendb[base + (size_t)s * DINNER] = f2bf(h[s]);
  sumdtb[(size_t)(b * NCH + c) * DINNER + d] = sumdt;
}

// ---------------- scan pass B: prefix over chunks; bf16 in/out; 16-deep load batches ----------------
__global__ void k_scan_B(const unsigned short* __restrict__ hendb,
                         const float* __restrict__ sumdtb,
                         const float* __restrict__ Alog,
                         unsigned short* __restrict__ hinb)
{
  int gid = blockIdx.x * 256 + threadIdx.x;  // B*DSTATE*DINNER = 65536
  int d = gid & (DINNER - 1);
  int s = (gid >> 11) & (DSTATE - 1);
  int b = gid >> 15;
  const float As = -__expf(Alog[d * DSTATE + s]);
  float h = 0.f;
  for (int c0 = 0; c0 < NCH; c0 += 16) {
    float he[16], sd[16];
    #pragma unroll
    for (int i = 0; i < 16; ++i) {
      he[i] = bf2f(hendb[((size_t)(b * NCH + c0 + i) * DSTATE + s) * DINNER + d]);
      sd[i] = sumdtb[(size_t)(b * NCH + c0 + i) * DINNER + d];
    }
    #pragma unroll
    for (int i = 0; i < 16; ++i) {
      hinb[((size_t)(b * NCH + c0 + i) * DSTATE + s) * DINNER + d] = f2bf(h);
      h = __expf(sd[i] * As) * h + he[i];
    }
  }
}

// ---------------- scan pass C: replay + fused epilogue ----------------
__global__ __launch_bounds__(256) void k_scan_C(
    const unsigned short* __restrict__ dtb, const unsigned short* __restrict__ xcb,
    const float* __restrict__ dbl, const float* __restrict__ Alog,
    const unsigned short* __restrict__ hinb, const float* __restrict__ Dskip,
    const unsigned short* __restrict__ xzb, unsigned short* __restrict__ yact)
{
  __shared__ __attribute__((aligned(16))) float bc[LC][32];  // [step][B0..15,C0..15]
  int gid = blockIdx.x * 256 + threadIdx.x;
  int d = gid & (DINNER - 1);
  int t = gid >> 11;
  int c = t & (NCH - 1);
  int b = t >> 6;
  const int r0 = b * SEQL + c * LC;
  {
    int step = threadIdx.x >> 4, j = (threadIdx.x & 15) * 2;
    float2 v = *(const float2*)&dbl[(size_t)(r0 + step) * 128 + 64 + j];
    bc[step][j] = v.x; bc[step][j + 1] = v.y;
  }
  float As[DSTATE];
  #pragma unroll
  for (int i = 0; i < 4; ++i) {
    f32x4 a = *(const f32x4*)&Alog[d * DSTATE + i * 4];
    #pragma unroll
    for (int j = 0; j < 4; ++j) As[i * 4 + j] = -__expf(a[j]);
  }
  float h[DSTATE];
  size_t base = ((size_t)(b * NCH + c) * DSTATE) * DINNER + d;
  #pragma unroll
  for (int s = 0; s < DSTATE; ++s) h[s] = bf2f(hinb[base + (size_t)s * DINNER]);
  const float dsk = Dskip[d];
  __syncthreads();
  #pragma unroll
  for (int li = 0; li < LC; li += 2) {
    const int r = r0 + li;
    float dt0 = bf2f(dtb[(size_t)r * DINNER + d]);
    float xv0 = bf2f(xcb[(size_t)r * DINNER + d]);
    float zv0 = bf2f(xzb[(size_t)r * 4096 + 2048 + d]);
    float dt1 = bf2f(dtb[(size_t)(r + 1) * DINNER + d]);
    float xv1 = bf2f(xcb[(size_t)(r + 1) * DINNER + d]);
    float zv1 = bf2f(xzb[(size_t)(r + 1) * 4096 + 2048 + d]);
    f32x4 B0[4], C0[4], B1[4], C1[4];
    #pragma unroll
    for (int i = 0; i < 4; ++i) B0[i] = *(const f32x4*)&bc[li][i * 4];
    #pragma unroll
    for (int i = 0; i < 4; ++i) C0[i] = *(const f32x4*)&bc[li][16 + i * 4];
    #pragma unroll
    for (int i = 0; i < 4; ++i) B1[i] = *(const f32x4*)&bc[li + 1][i * 4];
    #pragma unroll
    for (int i = 0; i < 4; ++i) C1[i] = *(const f32x4*)&bc[li + 1][16 + i * 4];
    const float* Bv0 = (const float*)B0; const float* Cv0 = (const float*)C0;
    const float* Bv1 = (const float*)B1; const float* Cv1 = (const float*)C1;
    float dtx0 = dt0 * xv0, dtx1 = dt1 * xv1;
    float y0 = 0.f, y1 = 0.f;
    #pragma unroll
    for (int s = 0; s < DSTATE; ++s) {
      float dA0 = __expf(dt0 * As[s]);
      h[s] = dA0 * h[s] + dtx0 * Bv0[s];
      y0 += h[s] * Cv0[s];
      float dA1 = __expf(dt1 * As[s]);
      h[s] = dA1 * h[s] + dtx1 * Bv1[s];
      y1 += h[s] * Cv1[s];
    }
    y0 += xv0 * dsk;
    y1 += xv1 * dsk;
    float ya0 = y0 * (zv0 * sigmoidf_(zv0));
    float ya1 = y1 * (zv1 * sigmoidf_(zv1));
    yact[(size_t)r * DINNER + d] = f2bf(ya0);
    yact[(size_t)(r + 1) * DINNER + d] = f2bf(ya1);
  }
}

extern "C" void kernel_launch(void* const* d_in, const int* in_sizes, int n_in,
                              void* d_out, int out_size, void* d_ws, size_t ws_size,
                              hipStream_t stream) {
  const float* x     = (const float*)d_in[0];
  const float* Win   = (const float*)d_in[1];
  const float* cw    = (const float*)d_in[2];
  const float* cbias = (const float*)d_in[3];
  const float* Wx    = (const float*)d_in[4];
  const float* Wdt   = (const float*)d_in[5];
  const float* bdt   = (const float*)d_in[6];
  const float* Alog  = (const float*)d_in[7];
  const float* Dsk   = (const float*)d_in[8];
  const float* Wout  = (const float*)d_in[9];
  float* out = (float*)d_out;

  char* ws = (char*)d_ws;
  const size_t MB = 1 << 20;
  // fully disjoint layout (r14/r16-proven map; part2/part5/dtraw retired)
  unsigned short* xzb   = (unsigned short*)(ws);               // 16 MB
  unsigned short* xbf   = (unsigned short*)(ws + 16 * MB);     //  4 MB
  unsigned short* wint  = (unsigned short*)(ws + 20 * MB);     //  8 MB
  unsigned short* xcb   = (unsigned short*)(ws + 28 * MB);     //  8 MB
  unsigned short* wxt   = (unsigned short*)(ws + 36 * MB);     //  0.5 MB
  float*          dbl   = (float*)         (ws + 37 * MB);     //  1 MB
  unsigned short* wdtt  = (unsigned short*)(ws + 39 * MB);     //  0.25 MB
  unsigned short* dtb16 = (unsigned short*)(ws + 40 * MB);     //  8 MB
  unsigned short* hendb = (unsigned short*)(ws + 48 * MB);     //  8 MB (bf16)
  float*          sumdt = (float*)         (ws + 56 * MB);     //  1 MB
  unsigned short* hinb  = (unsigned short*)(ws + 57 * MB);     //  8 MB (bf16)
  unsigned short* yact  = (unsigned short*)(ws + 65 * MB);     //  8 MB
  unsigned short* woutt = (unsigned short*)(ws + 73 * MB);     //  4 MB
  (void)ws_size; (void)in_sizes; (void)n_in; (void)out_size;

  // prep1: x->bf16 | W_in^T | zero(out) | zero(dbl)
  k_prep1<<<4352, 256, 0, stream>>>(x, xbf, Win, wint, out, dbl);
  // GEMM1 (128x64 tile, 1024 blocks): xzb bf16 = x @ W_in  (M=2048, N=4096, K=1024)
  k_gemm_n64<<<dim3(16, 64, 1), 256, 0, stream>>>(xbf, wint, nullptr, xzb, 2048, 4096, 1024, nullptr, 2);
  // conv + SiLU merged with W_out^T / W_dt^T / W_x pad^T
  k_conv_prep<<<3616, 256, 0, stream>>>(xzb, cw, cbias, xcb, Wout, woutt, Wdt, wdtt, Wx, wxt);
  // GEMM2 (mode 4, split 8): dbl += xc @ W_x_pad  (M=2048, N=128, K=2048; dbl pre-zeroed)
  k_gemm_n64<<<dim3(16, 2, 8), 256, 0, stream>>>(xcb, wxt, dbl, nullptr, 2048, 128, 2048, nullptr, 4);
  // GEMM3: dtb16 = bf16(softplus(dbl[:, :64] @ W_dt + b_dt))  (A reg-staged fp32->bf16)
  k_gemm_dt<<<dim3(16, 32), 256, 0, stream>>>(dbl, wdtt, dtb16, bdt);
  // chunked scan (NCH=64, LC=16), bf16 chunk summaries
  k_scan_A<<<1024, 256, 0, stream>>>(dtb16, xcb, dbl, Alog, hendb, sumdt);
  k_scan_B<<<256, 256, 0, stream>>>(hendb, sumdt, Alog, hinb);
  k_scan_C<<<1024, 256, 0, stream>>>(dtb16, xcb, dbl, Alog, hinb, Dsk, xzb, yact);
  // GEMM5 (mode 4, split 2): out += y_act @ W_out  (M=2048, N=1024, K=2048; out pre-zeroed)
  k_gemm_n64<<<dim3(16, 16, 2), 256, 0, stream>>>(yact, woutt, out, nullptr, 2048, 1024, 2048, nullptr, 4);
}

// Round 18
// 135.323 us; speedup vs baseline: 1.0530x; 1.0530x over previous
//
#include <hip/hip_runtime.h>

#define BATCH 2
#define SEQL 1024
#define DMODEL 1024
#define DINNER 2048
#define DSTATE 16
#define DTRANK 64
#define NCH 64
#define LC 16   // SEQL / NCH

typedef short bf16x8 __attribute__((ext_vector_type(8)));
typedef float f32x4 __attribute__((ext_vector_type(4)));
typedef int i32x4 __attribute__((ext_vector_type(4)));

__device__ __forceinline__ unsigned short f2bf(float f) {
  unsigned u = __float_as_uint(f);
  return (unsigned short)((u + 0x7fffu + ((u >> 16) & 1u)) >> 16);
}
__device__ __forceinline__ float bf2f(unsigned short u) {
  return __uint_as_float((unsigned)u << 16);
}
__device__ __forceinline__ float sigmoidf_(float x) { return 1.f / (1.f + __expf(-x)); }

__device__ __forceinline__ void gl_lds16(const unsigned short* g, unsigned short* l) {
  __builtin_amdgcn_global_load_lds(
      (const __attribute__((address_space(1))) unsigned int*)g,
      (__attribute__((address_space(3))) unsigned int*)l, 16, 0, 0);
}

// ---------------- 128x64-tile MFMA GEMM ----------------
// mode 0: fp32 slice per blockIdx.z | mode 1: bf16(softplus(acc+bias)) | mode 2: bf16 direct
// mode 3: bf16 slice per blockIdx.z.  XCD-bijective swizzle; (gx*gy) % 8 == 0.
__global__ __launch_bounds__(256) void k_gemm_n64(
    const unsigned short* __restrict__ A,   // [M][K] bf16 bits
    const unsigned short* __restrict__ Bt,  // [N][K] bf16 bits
    float* __restrict__ C, unsigned short* __restrict__ C2,
    int M, int N, int K, const float* __restrict__ bias, int mode)
{
  __shared__ __attribute__((aligned(16))) unsigned short As[128 * 64];
  __shared__ __attribute__((aligned(16))) unsigned short Bs[64 * 64];
  const int tid = threadIdx.x;
  const int wave = tid >> 6, lane = tid & 63;
  const int gx = gridDim.x;
  const int nwg = gx * gridDim.y;
  const int flat = blockIdx.x + gx * blockIdx.y;
  const int sw = (flat & 7) * (nwg >> 3) + (flat >> 3);
  const int m0 = (sw % gx) * 128, n0 = (sw / gx) * 64;
  const int Kc = K / gridDim.z;
  const int k0beg = blockIdx.z * Kc;
  float* Cz = C + (size_t)blockIdx.z * M * N;
  unsigned short* C2z = C2 + (size_t)blockIdx.z * M * N;
  const int wr = (wave & 1) * 64, wc = (wave >> 1) * 32;
  const int fr = lane & 15;
  const int qw = lane >> 4;

  int srowA[4], scolA[4];
  #pragma unroll
  for (int i = 0; i < 4; ++i) {
    int off = wave * 4096 + i * 1024 + lane * 16;
    int row = off >> 7;
    int c16 = ((off >> 4) & 7) ^ (row & 7);
    srowA[i] = row;
    scolA[i] = c16 * 8;
  }
  int srowB[2], scolB[2];
  #pragma unroll
  for (int i = 0; i < 2; ++i) {
    int off = wave * 2048 + i * 1024 + lane * 16;
    int row = off >> 7;
    int c16 = ((off >> 4) & 7) ^ (row & 7);
    srowB[i] = row;
    scolB[i] = c16 * 8;
  }

  f32x4 acc[4][2] = {};
  for (int k0 = k0beg; k0 < k0beg + Kc; k0 += 64) {
    #pragma unroll
    for (int i = 0; i < 4; ++i)
      gl_lds16(A + (size_t)(m0 + srowA[i]) * K + k0 + scolA[i],
               &As[(wave * 4096 + i * 1024) >> 1]);
    #pragma unroll
    for (int i = 0; i < 2; ++i)
      gl_lds16(Bt + (size_t)(n0 + srowB[i]) * K + k0 + scolB[i],
               &Bs[(wave * 2048 + i * 1024) >> 1]);
    __syncthreads();
    #pragma unroll
    for (int t = 0; t < 2; ++t) {
      bf16x8 af[4], bfv[2];
      #pragma unroll
      for (int i = 0; i < 4; ++i) {
        int row = wr + i * 16 + fr;
        int c16 = (t * 4 + qw) ^ (row & 7);
        af[i] = *(const bf16x8*)&As[row * 64 + c16 * 8];
      }
      #pragma unroll
      for (int j = 0; j < 2; ++j) {
        int row = wc + j * 16 + fr;
        int c16 = (t * 4 + qw) ^ (row & 7);
        bfv[j] = *(const bf16x8*)&Bs[row * 64 + c16 * 8];
      }
      #pragma unroll
      for (int i = 0; i < 4; ++i)
        #pragma unroll
        for (int j = 0; j < 2; ++j)
          acc[i][j] = __builtin_amdgcn_mfma_f32_16x16x32_bf16(af[i], bfv[j], acc[i][j], 0, 0, 0);
    }
    __syncthreads();
  }
  const int rr = qw * 4;
  if (mode == 0) {
    #pragma unroll
    for (int i = 0; i < 4; ++i)
      #pragma unroll
      for (int j = 0; j < 2; ++j)
        #pragma unroll
        for (int r = 0; r < 4; ++r)
          Cz[(size_t)(m0 + wr + i * 16 + rr + r) * N + (n0 + wc + j * 16 + fr)] =
              acc[i][j][r];
  } else if (mode == 1) {
    #pragma unroll
    for (int j = 0; j < 2; ++j) {
      float bj = bias[n0 + wc + j * 16 + fr];
      #pragma unroll
      for (int i = 0; i < 4; ++i)
        #pragma unroll
        for (int r = 0; r < 4; ++r) {
          float v = acc[i][j][r] + bj;
          C2[(size_t)(m0 + wr + i * 16 + rr + r) * N + (n0 + wc + j * 16 + fr)] =
              f2bf(__logf(1.f + __expf(v)));
        }
    }
  } else if (mode == 2) {
    #pragma unroll
    for (int i = 0; i < 4; ++i)
      #pragma unroll
      for (int j = 0; j < 2; ++j)
        #pragma unroll
        for (int r = 0; r < 4; ++r)
          C2[(size_t)(m0 + wr + i * 16 + rr + r) * N + (n0 + wc + j * 16 + fr)] =
              f2bf(acc[i][j][r]);
  } else {
    #pragma unroll
    for (int i = 0; i < 4; ++i)
      #pragma unroll
      for (int j = 0; j < 2; ++j)
        #pragma unroll
        for (int r = 0; r < 4; ++r)
          C2z[(size_t)(m0 + wr + i * 16 + rr + r) * N + (n0 + wc + j * 16 + fr)] =
              f2bf(acc[i][j][r]);
  }
}

// ---------------- shared transpose tile helper ----------------
__device__ __forceinline__ void transpose_tile(
    const float* __restrict__ src, unsigned short* __restrict__ dst,
    int R, int C, int bx, int by, float* t /* [64][65] */)
{
  int bc = bx * 64, br = by * 64;
  int tr = threadIdx.x >> 2;
  int tc = (threadIdx.x & 3) * 16;
  #pragma unroll
  for (int i = 0; i < 4; ++i) {
    float4 v = *(const float4*)(src + (size_t)(br + tr) * C + bc + tc + i * 4);
    t[tr * 65 + tc + i * 4 + 0] = v.x; t[tr * 65 + tc + i * 4 + 1] = v.y;
    t[tr * 65 + tc + i * 4 + 2] = v.z; t[tr * 65 + tc + i * 4 + 3] = v.w;
  }
  __syncthreads();
  unsigned short tmp[16];
  #pragma unroll
  for (int i = 0; i < 16; ++i) tmp[i] = f2bf(t[(tc + i) * 65 + tr]);
  unsigned short* dp = dst + (size_t)(bc + tr) * R + br + tc;
  *(i32x4*)dp = *(i32x4*)&tmp[0];
  *(i32x4*)(dp + 8) = *(i32x4*)&tmp[8];
}

// ---------------- prep1: x->bf16 + W_in^T ----------------
__global__ __launch_bounds__(256) void k_prep1(
    const float* __restrict__ x,   unsigned short* __restrict__ xbf,
    const float* __restrict__ Win, unsigned short* __restrict__ wint)
{
  __shared__ float t[64 * 65];
  int bid = blockIdx.x;
  if (bid < 1024) {
    int i = (bid * 256 + threadIdx.x) * 8;
    float4 a = *(const float4*)(x + i);
    float4 b = *(const float4*)(x + i + 4);
    unsigned short tmp[8] = {f2bf(a.x), f2bf(a.y), f2bf(a.z), f2bf(a.w),
                             f2bf(b.x), f2bf(b.y), f2bf(b.z), f2bf(b.w)};
    *(i32x4*)(xbf + i) = *(i32x4*)tmp;
  } else {
    int tt = bid - 1024;
    transpose_tile(Win, wint, 1024, 4096, tt & 63, tt >> 6, t);
  }
}

// ---------------- conv + SiLU merged with remaining weight prep ----------------
__global__ __launch_bounds__(256) void k_conv_prep(
    const unsigned short* __restrict__ xzb, const float* __restrict__ cw,
    const float* __restrict__ cb, unsigned short* __restrict__ xcb,
    const float* __restrict__ Wout, unsigned short* __restrict__ woutt,
    const float* __restrict__ Wdt,  unsigned short* __restrict__ wdtt,
    const float* __restrict__ Wx,   unsigned short* __restrict__ wxt)
{
  __shared__ float t[64 * 65];
  int bid = blockIdx.x;
  if (bid < 2048) {
    int idx = (bid * 256 + threadIdx.x) * 8;
    int d0 = idx & (DINNER - 1);
    int bl = idx >> 11;
    int l = bl & (SEQL - 1);
    float s[8];
    {
      float4 c0 = *(const float4*)(cb + d0);
      float4 c1 = *(const float4*)(cb + d0 + 4);
      s[0] = c0.x; s[1] = c0.y; s[2] = c0.z; s[3] = c0.w;
      s[4] = c1.x; s[5] = c1.y; s[6] = c1.z; s[7] = c1.w;
    }
    float4 w[8];
    #pragma unroll
    for (int i = 0; i < 8; ++i) w[i] = *(const float4*)(cw + (d0 + i) * 4);
    #pragma unroll
    for (int k = 0; k < 4; ++k) {
      int ll = l - 3 + k;
      if (ll >= 0) {
        bf16x8 v = *(const bf16x8*)&xzb[(size_t)(bl - 3 + k) * 4096 + d0];
        #pragma unroll
        for (int i = 0; i < 8; ++i)
          s[i] += bf2f((unsigned short)v[i]) * ((const float*)&w[i])[k];
      }
    }
    unsigned short o[8];
    #pragma unroll
    for (int i = 0; i < 8; ++i) {
      float r = s[i] * sigmoidf_(s[i]);
      o[i] = f2bf(r);
    }
    *(i32x4*)&xcb[idx] = *(i32x4*)o;
  } else if (bid < 2560) {
    int tt = bid - 2048;
    transpose_tile(Wout, woutt, 2048, 1024, tt & 15, tt >> 4, t);
  } else if (bid < 2592) {
    int tt = bid - 2560;
    transpose_tile(Wdt, wdtt, 64, 2048, tt, 0, t);
  } else {
    int idx = (bid - 2592) * 256 + threadIdx.x;
    int k = idx & (DINNER - 1);
    int n = idx >> 11;
    float v = (n < 96) ? Wx[(size_t)k * 96 + n] : 0.f;
    wxt[idx] = f2bf(v);
  }
}

// ---------------- reduce 8 split-K fp32 partials -> dbl fp32; fused dt-col extract (x4 vec) ----------------
__global__ void k_reduce2(const float* __restrict__ part, float* __restrict__ dbl,
                          unsigned short* __restrict__ dtraw)
{
  int idx = (blockIdx.x * 256 + threadIdx.x) * 4;  // over 2048*128
  f32x4 s = *(const f32x4*)(part + idx);
  #pragma unroll
  for (int z = 1; z < 8; ++z) s += *(const f32x4*)(part + (size_t)z * 2048 * 128 + idx);
  *(f32x4*)(dbl + idx) = s;
  int col = idx & 127, rw = idx >> 7;
  if (col < 64) {
    unsigned short tmp[4] = {f2bf(s[0]), f2bf(s[1]), f2bf(s[2]), f2bf(s[3])};
    *(unsigned long long*)(dtraw + rw * 64 + col) = *(unsigned long long*)tmp;
  }
}

// ---------------- reduce 2 split-K bf16 partials -> out fp32 (8/thread) ----------------
__global__ void k_reduce5(const unsigned short* __restrict__ part, float* __restrict__ out)
{
  int idx = (blockIdx.x * 256 + threadIdx.x) * 8;  // over 2048*1024
  float s[8] = {};
  #pragma unroll
  for (int z = 0; z < 2; ++z) {
    bf16x8 v = *(const bf16x8*)(part + (size_t)z * 2048 * 1024 + idx);
    #pragma unroll
    for (int i = 0; i < 8; ++i) s[i] += bf2f((unsigned short)v[i]);
  }
  *(f32x4*)(out + idx) = *(f32x4*)&s[0];
  *(f32x4*)(out + idx + 4) = *(f32x4*)&s[4];
}

// ---------------- scan pass A: local scan; hend bf16 + sumdt fp32 ----------------
__global__ __launch_bounds__(256) void k_scan_A(
    const unsigned short* __restrict__ dtb, const unsigned short* __restrict__ xcb,
    const float* __restrict__ dbl, const float* __restrict__ Alog,
    unsigned short* __restrict__ hendb, float* __restrict__ sumdtb)
{
  __shared__ __attribute__((aligned(16))) float bcB[LC][DSTATE];
  int gid = blockIdx.x * 256 + threadIdx.x;  // over B*NCH*DINNER = 262144
  int d = gid & (DINNER - 1);
  int t = gid >> 11;
  int c = t & (NCH - 1);
  int b = t >> 6;
  const int r0 = b * SEQL + c * LC;
  bcB[threadIdx.x >> 4][threadIdx.x & 15] =
      dbl[(size_t)(r0 + (threadIdx.x >> 4)) * 128 + 64 + (threadIdx.x & 15)];
  float As[DSTATE];
  #pragma unroll
  for (int i = 0; i < 4; ++i) {
    f32x4 a = *(const f32x4*)&Alog[d * DSTATE + i * 4];
    #pragma unroll
    for (int j = 0; j < 4; ++j) As[i * 4 + j] = -__expf(a[j]);
  }
  __syncthreads();
  float h[DSTATE];
  #pragma unroll
  for (int s = 0; s < DSTATE; ++s) h[s] = 0.f;
  float sumdt = 0.f;
  #pragma unroll
  for (int li = 0; li < LC; li += 2) {
    float dt0 = bf2f(dtb[(size_t)(r0 + li) * DINNER + d]);
    float xv0 = bf2f(xcb[(size_t)(r0 + li) * DINNER + d]);
    float dt1 = bf2f(dtb[(size_t)(r0 + li + 1) * DINNER + d]);
    float xv1 = bf2f(xcb[(size_t)(r0 + li + 1) * DINNER + d]);
    f32x4 B0[4], B1[4];
    #pragma unroll
    for (int i = 0; i < 4; ++i) B0[i] = *(const f32x4*)&bcB[li][i * 4];
    #pragma unroll
    for (int i = 0; i < 4; ++i) B1[i] = *(const f32x4*)&bcB[li + 1][i * 4];
    float dtx0 = dt0 * xv0, dtx1 = dt1 * xv1;
    sumdt += dt0 + dt1;
    const float* Bv0 = (const float*)B0;
    const float* Bv1 = (const float*)B1;
    #pragma unroll
    for (int s = 0; s < DSTATE; ++s) {
      float dA0 = __expf(dt0 * As[s]);
      h[s] = dA0 * h[s] + dtx0 * Bv0[s];
      float dA1 = __expf(dt1 * As[s]);
      h[s] = dA1 * h[s] + dtx1 * Bv1[s];
    }
  }
  size_t base = ((size_t)(b * NCH + c) * DSTATE) * DINNER + d;
  #pragma unroll
  for (int s = 0; s < DSTATE; ++s) hendb[base + (size_t)s * DINNER] = f2bf(h[s]);
  sumdtb[(size_t)(b * NCH + c) * DINNER + d] = sumdt;
}

// ---------------- scan pass B: prefix over chunks; bf16 in/out; 16-deep load batches ----------------
__global__ void k_scan_B(const unsigned short* __restrict__ hendb,
                         const float* __restrict__ sumdtb,
                         const float* __restrict__ Alog,
                         unsigned short* __restrict__ hinb)
{
  int gid = blockIdx.x * 256 + threadIdx.x;  // B*DSTATE*DINNER = 65536
  int d = gid & (DINNER - 1);
  int s = (gid >> 11) & (DSTATE - 1);
  int b = gid >> 15;
  const float As = -__expf(Alog[d * DSTATE + s]);
  float h = 0.f;
  for (int c0 = 0; c0 < NCH; c0 += 16) {
    float he[16], sd[16];
    #pragma unroll
    for (int i = 0; i < 16; ++i) {
      he[i] = bf2f(hendb[((size_t)(b * NCH + c0 + i) * DSTATE + s) * DINNER + d]);
      sd[i] = sumdtb[(size_t)(b * NCH + c0 + i) * DINNER + d];
    }
    #pragma unroll
    for (int i = 0; i < 16; ++i) {
      hinb[((size_t)(b * NCH + c0 + i) * DSTATE + s) * DINNER + d] = f2bf(h);
      h = __expf(sd[i] * As) * h + he[i];
    }
  }
}

// ---------------- scan pass C: replay + fused epilogue ----------------
__global__ __launch_bounds__(256) void k_scan_C(
    const unsigned short* __restrict__ dtb, const unsigned short* __restrict__ xcb,
    const float* __restrict__ dbl, const float* __restrict__ Alog,
    const unsigned short* __restrict__ hinb, const float* __restrict__ Dskip,
    const unsigned short* __restrict__ xzb, unsigned short* __restrict__ yact)
{
  __shared__ __attribute__((aligned(16))) float bc[LC][32];  // [step][B0..15,C0..15]
  int gid = blockIdx.x * 256 + threadIdx.x;
  int d = gid & (DINNER - 1);
  int t = gid >> 11;
  int c = t & (NCH - 1);
  int b = t >> 6;
  const int r0 = b * SEQL + c * LC;
  {
    int step = threadIdx.x >> 4, j = (threadIdx.x & 15) * 2;
    float2 v = *(const float2*)&dbl[(size_t)(r0 + step) * 128 + 64 + j];
    bc[step][j] = v.x; bc[step][j + 1] = v.y;
  }
  float As[DSTATE];
  #pragma unroll
  for (int i = 0; i < 4; ++i) {
    f32x4 a = *(const f32x4*)&Alog[d * DSTATE + i * 4];
    #pragma unroll
    for (int j = 0; j < 4; ++j) As[i * 4 + j] = -__expf(a[j]);
  }
  float h[DSTATE];
  size_t base = ((size_t)(b * NCH + c) * DSTATE) * DINNER + d;
  #pragma unroll
  for (int s = 0; s < DSTATE; ++s) h[s] = bf2f(hinb[base + (size_t)s * DINNER]);
  const float dsk = Dskip[d];
  __syncthreads();
  #pragma unroll
  for (int li = 0; li < LC; li += 2) {
    const int r = r0 + li;
    float dt0 = bf2f(dtb[(size_t)r * DINNER + d]);
    float xv0 = bf2f(xcb[(size_t)r * DINNER + d]);
    float zv0 = bf2f(xzb[(size_t)r * 4096 + 2048 + d]);
    float dt1 = bf2f(dtb[(size_t)(r + 1) * DINNER + d]);
    float xv1 = bf2f(xcb[(size_t)(r + 1) * DINNER + d]);
    float zv1 = bf2f(xzb[(size_t)(r + 1) * 4096 + 2048 + d]);
    f32x4 B0[4], C0[4], B1[4], C1[4];
    #pragma unroll
    for (int i = 0; i < 4; ++i) B0[i] = *(const f32x4*)&bc[li][i * 4];
    #pragma unroll
    for (int i = 0; i < 4; ++i) C0[i] = *(const f32x4*)&bc[li][16 + i * 4];
    #pragma unroll
    for (int i = 0; i < 4; ++i) B1[i] = *(const f32x4*)&bc[li + 1][i * 4];
    #pragma unroll
    for (int i = 0; i < 4; ++i) C1[i] = *(const f32x4*)&bc[li + 1][16 + i * 4];
    const float* Bv0 = (const float*)B0; const float* Cv0 = (const float*)C0;
    const float* Bv1 = (const float*)B1; const float* Cv1 = (const float*)C1;
    float dtx0 = dt0 * xv0, dtx1 = dt1 * xv1;
    float y0 = 0.f, y1 = 0.f;
    #pragma unroll
    for (int s = 0; s < DSTATE; ++s) {
      float dA0 = __expf(dt0 * As[s]);
      h[s] = dA0 * h[s] + dtx0 * Bv0[s];
      y0 += h[s] * Cv0[s];
      float dA1 = __expf(dt1 * As[s]);
      h[s] = dA1 * h[s] + dtx1 * Bv1[s];
      y1 += h[s] * Cv1[s];
    }
    y0 += xv0 * dsk;
    y1 += xv1 * dsk;
    float ya0 = y0 * (zv0 * sigmoidf_(zv0));
    float ya1 = y1 * (zv1 * sigmoidf_(zv1));
    yact[(size_t)r * DINNER + d] = f2bf(ya0);
    yact[(size_t)(r + 1) * DINNER + d] = f2bf(ya1);
  }
}

extern "C" void kernel_launch(void* const* d_in, const int* in_sizes, int n_in,
                              void* d_out, int out_size, void* d_ws, size_t ws_size,
                              hipStream_t stream) {
  const float* x     = (const float*)d_in[0];
  const float* Win   = (const float*)d_in[1];
  const float* cw    = (const float*)d_in[2];
  const float* cbias = (const float*)d_in[3];
  const float* Wx    = (const float*)d_in[4];
  const float* Wdt   = (const float*)d_in[5];
  const float* bdt   = (const float*)d_in[6];
  const float* Alog  = (const float*)d_in[7];
  const float* Dsk   = (const float*)d_in[8];
  const float* Wout  = (const float*)d_in[9];
  float* out = (float*)d_out;

  char* ws = (char*)d_ws;
  const size_t MB = 1 << 20;
  // fully disjoint layout, 93 MB total. NO aliasing. (r12/r14/r16-proven map)
  unsigned short* xzb   = (unsigned short*)(ws);               // 16 MB
  unsigned short* xbf   = (unsigned short*)(ws + 16 * MB);     //  4 MB
  unsigned short* wint  = (unsigned short*)(ws + 20 * MB);     //  8 MB
  unsigned short* xcb   = (unsigned short*)(ws + 28 * MB);     //  8 MB
  unsigned short* wxt   = (unsigned short*)(ws + 36 * MB);     //  0.5 MB
  float*          dbl   = (float*)         (ws + 37 * MB);     //  1 MB
  unsigned short* dtraw = (unsigned short*)(ws + 38 * MB);     //  0.25 MB
  unsigned short* wdtt  = (unsigned short*)(ws + 39 * MB);     //  0.25 MB
  unsigned short* dtb16 = (unsigned short*)(ws + 40 * MB);     //  8 MB
  unsigned short* hendb = (unsigned short*)(ws + 48 * MB);     //  8 MB (bf16)
  float*          sumdt = (float*)         (ws + 56 * MB);     //  1 MB
  unsigned short* hinb  = (unsigned short*)(ws + 57 * MB);     //  8 MB (bf16)
  unsigned short* yact  = (unsigned short*)(ws + 65 * MB);     //  8 MB
  unsigned short* woutt = (unsigned short*)(ws + 73 * MB);     //  4 MB
  float*          part2 = (float*)         (ws + 77 * MB);     //  8 MB (8 x 1 MB fp32)
  unsigned short* part5 = (unsigned short*)(ws + 85 * MB);     //  8 MB (2 x 4 MB bf16)
  (void)ws_size; (void)in_sizes; (void)n_in; (void)out_size;

  // prep1: only GEMM1's deps (x->bf16, W_in^T)
  k_prep1<<<2048, 256, 0, stream>>>(x, xbf, Win, wint);
  // GEMM1 (128x64 tile, 1024 blocks): xzb bf16 = x @ W_in  (M=2048, N=4096, K=1024)
  k_gemm_n64<<<dim3(16, 64, 1), 256, 0, stream>>>(xbf, wint, nullptr, xzb, 2048, 4096, 1024, nullptr, 2);
  // conv + SiLU merged with W_out^T / W_dt^T / W_x pad^T
  k_conv_prep<<<3616, 256, 0, stream>>>(xzb, cw, cbias, xcb, Wout, woutt, Wdt, wdtt, Wx, wxt);
  // GEMM2 (128x64 tile, split 8): part2[z] fp32 = xc @ W_x_pad  (M=2048, N=128, K=2048)
  k_gemm_n64<<<dim3(16, 2, 8), 256, 0, stream>>>(xcb, wxt, part2, nullptr, 2048, 128, 2048, nullptr, 0);
  // reduce -> dbl fp32 + dt-col extract bf16 (vectorized x4)
  k_reduce2<<<256, 256, 0, stream>>>(part2, dbl, dtraw);
  // GEMM3 (128x64 tile, 512 blocks, mode 1): dtb16 = bf16(softplus(dt_raw @ W_dt + b_dt))
  k_gemm_n64<<<dim3(16, 32, 1), 256, 0, stream>>>(dtraw, wdtt, nullptr, dtb16, 2048, 2048, 64, bdt, 1);
  // chunked scan (NCH=64, LC=16), bf16 chunk summaries
  k_scan_A<<<1024, 256, 0, stream>>>(dtb16, xcb, dbl, Alog, hendb, sumdt);
  k_scan_B<<<256, 256, 0, stream>>>(hendb, sumdt, Alog, hinb);
  k_scan_C<<<1024, 256, 0, stream>>>(dtb16, xcb, dbl, Alog, hinb, Dsk, xzb, yact);
  // GEMM5 (128x64 tile, split 2): part5[z] bf16 = y_act @ W_out  (M=2048, N=1024, K=2048)
  k_gemm_n64<<<dim3(16, 16, 2), 256, 0, stream>>>(yact, woutt, nullptr, part5, 2048, 1024, 2048, nullptr, 3);
  // reduce bf16 partials -> out fp32
  k_reduce5<<<1024, 256, 0, stream>>>(part5, out);
}